// Round 7
// baseline (83.966 us; speedup 1.0000x reference)
//
#include <hip/hip_runtime.h>

#define BSZ  512
#define EPSF 1e-5f
#define NBLK 256

__device__ __forceinline__ float dist_xform(float v) {
    v = fmaxf(v, 0.0f);
    float z = (v == 0.0f) ? 1.0f : 0.0f;   // zmask per reference
    v = sqrtf(v + z * EPSF) + EPSF;
    return v * (1.0f - z);
}

// Triplet reduction for anchor a over its distance row (512-thread block).
__device__ __forceinline__ void triplet_phase(int a, const float* __restrict__ drow,
                                              const int* lab, int* poslist,
                                              int* npos_s, float* wsum, int* wcnt,
                                              float* __restrict__ partial, int tid) {
    if (tid == 0) *npos_s = 0;
    __syncthreads();
    const int la = lab[a];
    if (tid != a && lab[tid] == la) {          // tid spans 0..511 exactly
        int idx = atomicAdd(npos_s, 1);
        poslist[idx] = tid;
    }
    __syncthreads();
    const int npos = *npos_s;
    const int nneg = BSZ - 1 - npos;           // all other-label are valid negatives

    float sum = 0.0f;
    int   cnt = 0;
    const int total = npos * BSZ;
    for (int idx = tid; idx < total; idx += 512) {
        const int p = poslist[idx >> 9];       // broadcast within wave
        const int n = idx & (BSZ - 1);         // consecutive -> conflict-free
        if (lab[n] != la) {
            const float v = drow[p] - drow[n]; // margin = 0
            if (v > 0.0f)  sum += v;
            if (v > 1e-5f) cnt++;
        }
    }
#pragma unroll
    for (int off = 32; off > 0; off >>= 1) {
        sum += __shfl_down(sum, off);
        cnt += __shfl_down(cnt, off);
    }
    const int wave = tid >> 6, lane = tid & 63;
    if (lane == 0) { wsum[wave] = sum; wcnt[wave] = cnt; }
    __syncthreads();
    if (tid == 0) {
        float S = 0.0f; int C = 0;
#pragma unroll
        for (int w = 0; w < 8; ++w) { S += wsum[w]; C += wcnt[w]; }
        partial[a]           = S;
        partial[BSZ + a]     = (float)C;
        partial[2*BSZ + a]   = (float)npos * (float)nneg;
    }
    __syncthreads();   // protect npos_s/poslist/wsum reuse
}

// One kernel: block b computes full distance rows for anchors 2b, 2b+1
// (anchor slices in registers, stream E from L2), runs the triplet phase for
// both, then a decoupled last-block finale (single release fence + atomic —
// no spin barrier). 256 blocks x 512 threads = 8 waves/CU = 2 waves/SIMD.
__global__ __launch_bounds__(512, 2) void fused_kernel(const float* __restrict__ E,
                                                       const int* __restrict__ labels,
                                                       float* __restrict__ ws,
                                                       float* __restrict__ out) {
    const int tid = threadIdx.x;
    const int g = tid >> 4;            // j-group 0..31
    const int l = tid & 15;            // lane in group: 16 x 16B = 256B/row
    const int a0 = blockIdx.x * 2, a1 = a0 + 1;

    __shared__ float drow0[BSZ], drow1[BSZ];
    __shared__ int   lab[BSZ];
    __shared__ int   poslist[BSZ];
    __shared__ int   npos_s;
    __shared__ float wsum[8];
    __shared__ int   wcnt[8];
    __shared__ float wcf[8], wvf[8];
    __shared__ int   is_last;

    lab[tid] = labels[tid];            // 512 threads, one pass

    // Anchor rows -> registers: 8 float4 per anchor, slice c*16+l.
    const float4* r0 = (const float4*)(E + (size_t)a0 * BSZ);
    const float4* r1 = (const float4*)(E + (size_t)a1 * BSZ);
    float4 av0[8], av1[8];
#pragma unroll
    for (int c = 0; c < 8; ++c) { av0[c] = r0[c * 16 + l]; av1[c] = r1[c * 16 + l]; }

    // Distance phase: 32 j-rows in flight per pass, 16 lanes per row.
    for (int it = 0; it < 16; ++it) {
        const int j = it * 32 + g;
        const float4* rj = (const float4*)(E + (size_t)j * BSZ);
        float4 jv[8];
#pragma unroll
        for (int c = 0; c < 8; ++c) jv[c] = rj[c * 16 + l];   // 8 independent loads
        float s0 = 0.0f, s1 = 0.0f;
#pragma unroll
        for (int c = 0; c < 8; ++c) {
            float d;
            d = av0[c].x - jv[c].x; s0 = fmaf(d, d, s0);
            d = av0[c].y - jv[c].y; s0 = fmaf(d, d, s0);
            d = av0[c].z - jv[c].z; s0 = fmaf(d, d, s0);
            d = av0[c].w - jv[c].w; s0 = fmaf(d, d, s0);
            d = av1[c].x - jv[c].x; s1 = fmaf(d, d, s1);
            d = av1[c].y - jv[c].y; s1 = fmaf(d, d, s1);
            d = av1[c].z - jv[c].z; s1 = fmaf(d, d, s1);
            d = av1[c].w - jv[c].w; s1 = fmaf(d, d, s1);
        }
        // reduce across the 16 lanes of the group (stays within the wave)
        s0 += __shfl_xor(s0, 8); s0 += __shfl_xor(s0, 4);
        s0 += __shfl_xor(s0, 2); s0 += __shfl_xor(s0, 1);
        s1 += __shfl_xor(s1, 8); s1 += __shfl_xor(s1, 4);
        s1 += __shfl_xor(s1, 2); s1 += __shfl_xor(s1, 1);
        if (l == 0) {                  // j mod 32 = g -> distinct banks
            drow0[j] = dist_xform(s0);
            drow1[j] = dist_xform(s1);
        }
    }
    __syncthreads();

    float* partial = ws + 8;
    triplet_phase(a0, drow0, lab, poslist, &npos_s, wsum, wcnt, partial, tid);
    triplet_phase(a1, drow1, lab, poslist, &npos_s, wsum, wcnt, partial, tid);

    // Decoupled finale: single release fence + device-scope atomic per block.
    if (tid == 0) {
        __threadfence();                           // release partials device-wide
        unsigned old = atomicAdd((unsigned*)ws, 1u);
        is_last = (old == NBLK - 1) ? 1 : 0;
    }
    __syncthreads();

    if (is_last) {
        __threadfence();                           // acquire: invalidate stale lines
        float s = partial[tid];                    // 512 threads, one entry each
        float c = partial[BSZ + tid];
        float v = partial[2 * BSZ + tid];
#pragma unroll
        for (int off = 32; off > 0; off >>= 1) {
            s += __shfl_down(s, off);
            c += __shfl_down(c, off);
            v += __shfl_down(v, off);
        }
        const int wave = tid >> 6, lane = tid & 63;
        if (lane == 0) { wsum[wave] = s; wcf[wave] = c; wvf[wave] = v; }
        __syncthreads();
        if (tid == 0) {
            float S = 0.0f, C = 0.0f, V = 0.0f;
#pragma unroll
            for (int w = 0; w < 8; ++w) { S += wsum[w]; C += wcf[w]; V += wvf[w]; }
            out[0] = S / (C + 1e-5f);   // loss
            out[1] = C / (V + 1e-5f);   // fraction_positive
        }
    }
}

extern "C" void kernel_launch(void* const* d_in, const int* in_sizes, int n_in,
                              void* d_out, int out_size, void* d_ws, size_t ws_size,
                              hipStream_t stream) {
    const float* E      = (const float*)d_in[0];   // embeddings [512,512] fp32
    const int*   labels = (const int*)d_in[1];     // labels [512]
    float* out = (float*)d_out;
    float* ws  = (float*)d_ws;

    hipMemsetAsync(ws, 0, 8, stream);              // zero the finale counter
    fused_kernel<<<NBLK, 512, 0, stream>>>(E, labels, ws, out);
}